// Round 10
// baseline (1729.992 us; speedup 1.0000x reference)
//
#include <hip/hip_runtime.h>
#include <hip/hip_bf16.h>

// SkipGRU: B=64, T=4096, F=128, U=128, P=16 -> 1024 chains of length 256.
// Round-4 monolithic structure with TWO independent batches per WG:
// 32 WGs x 16 waves (1024 thr, forced 4 waves/SIMD). Waves 0-7 run batch
// 2*bid, waves 8-15 run batch 2*bid+1 -> two independent dependency streams
// per SIMD hide the per-step latency chain (ds_read -> h-MFMA -> gate ->
// ds_write -> barrier). Per-wave: one 16-col u-slice of all three gates;
// weights/gates/h-state in registers; x-MFMAs for step l+1 pipelined into
// the h-MFMA shadow; sigmoid via exp2 with log2e folded into weights.
// NOTE: __launch_bounds__(1024, 1) — a 1024-thr block forces <=128 VGPR;
// r6's (1024,4) acted like CUDA min-BLOCKS and spilled at 64 VGPR.

#define B_N 64
#define T_N 4096
#define F_N 128
#define U_N 128
#define P_N 16
#define L_N 256
#define NW 16
#define NT (NW * 64)   // 1024 threads

#define LOG2E 1.4426950408889634f

typedef _Float16 f16x8 __attribute__((ext_vector_type(8)));
typedef _Float16 f16x4 __attribute__((ext_vector_type(4)));
typedef float f32x4 __attribute__((ext_vector_type(4)));

__device__ __forceinline__ float sigmoid2_(float y) {   // y pre-scaled by log2e
    return __builtin_amdgcn_rcpf(1.0f + __builtin_amdgcn_exp2f(-y));
}

// Position of logical k within a fragment-contiguous row:
// row[kt*32 + lg*8 + e] holds k = kt*32 + 16*(e>>2) + 4*lg + (e&3).
__device__ __forceinline__ int fpos(int k) {
    return ((k >> 5) << 5) + (((k >> 2) & 3) << 3) + (((k >> 4) & 1) << 2) + (k & 3);
}

// barrier with LDS-only drain; global loads/stores stay in flight
#define BAR() do { \
    asm volatile("s_waitcnt lgkmcnt(0)" ::: "memory"); \
    __builtin_amdgcn_s_barrier(); \
    __builtin_amdgcn_sched_barrier(0); \
} while (0)

struct Acc { f32x4 z, r, xh, hh; };

__global__ __launch_bounds__(NT, 1) void skipgru_kernel(
    const float* __restrict__ xg, const float* __restrict__ Wk,
    const float* __restrict__ Wr, const float* __restrict__ bias,
    float* __restrict__ out)
{
    // Fragment-contiguous A operands per batch, padded rows (264 B) for banks.
    __shared__ __align__(16) _Float16 A_x[2][2][16][132];  // [bat][buf][m][k]
    __shared__ __align__(16) _Float16 A_h[2][2][16][132];

    const int tid  = threadIdx.x;
    const int lane = tid & 63;
    const int wave = tid >> 6;
    const int bat  = wave >> 3;      // which of the two batches in this WG
    const int ws   = wave & 7;       // wave-slice within the batch
    const int ln   = lane & 15;      // A-row / C-col index
    const int lg   = lane >> 4;      // k-group (A/B), row-group (C/D)
    const int u    = ws * 16 + ln;   // this lane's output column
    const int m0   = lg * 4;         // this lane's C/D row base
    const int b    = blockIdx.x * 2 + bat;
    const int hcol = fpos(u);        // A_h transpose-write column

    // --- per-lane bias scalars (z/r pre-summed and log2e-scaled)
    const float bz  = (bias[u]       + bias[384 + u])       * LOG2E;
    const float br  = (bias[128 + u] + bias[384 + 128 + u]) * LOG2E;
    const float bxh = bias[256 + u];
    const float brh = bias[384 + 256 + u];

    // --- weight fragments: 6 B-frag sets (z/r/h x Wk/Wr); z/r scaled by log2e
    f16x8 wzk[4], wzr[4], wrk[4], wrr[4], whk[4], whr[4];
    #pragma unroll
    for (int kt = 0; kt < 4; ++kt) {
        #pragma unroll
        for (int e = 0; e < 8; ++e) {
            int k = kt * 32 + ((e >> 2) << 4) + (lg << 2) + (e & 3);
            const float* wkp = Wk + (size_t)k * 384;
            const float* wrp = Wr + (size_t)k * 384;
            wzk[kt][e] = (_Float16)(wkp[u] * LOG2E);
            wzr[kt][e] = (_Float16)(wrp[u] * LOG2E);
            wrk[kt][e] = (_Float16)(wkp[128 + u] * LOG2E);
            wrr[kt][e] = (_Float16)(wrp[128 + u] * LOG2E);
            whk[kt][e] = (_Float16)wkp[256 + u];
            whr[kt][e] = (_Float16)wrp[256 + u];
        }
    }

    // --- zero A_h[bat][0] (h(-P) = 0): each 512-thread half does its batch
    const int lt = tid & 511;        // thread id within the batch half
    for (int q = lt; q < 16 * 132; q += 512)
        ((_Float16*)A_h[bat][0])[q] = (_Float16)0;

    // --- x staging map: half-local thread -> (row sm, col-quad sc)
    const int sm = lt & 15, sc = (lt >> 4) << 2;
    const int scp = fpos(sc);        // sc%4==0 -> 4 consecutive frag slots
    const float* xb = xg + (size_t)b * T_N * F_N;
    {
        float4 x0 = *(const float4*)(xb + (size_t)sm * F_N + sc);
        float4 x1 = *(const float4*)(xb + (size_t)(P_N + sm) * F_N + sc);
        f16x4 v0 = {(_Float16)x0.x, (_Float16)x0.y, (_Float16)x0.z, (_Float16)x0.w};
        f16x4 v1 = {(_Float16)x1.x, (_Float16)x1.y, (_Float16)x1.z, (_Float16)x1.w};
        *(f16x4*)&A_x[bat][0][sm][scp] = v0;
        *(f16x4*)&A_x[bat][1][sm][scp] = v1;
    }
    float4 xsB = *(const float4*)(xb + (size_t)(2 * P_N + sm) * F_N + sc);  // L(2)
    float4 xsA = *(const float4*)(xb + (size_t)(3 * P_N + sm) * F_N + sc);  // L(3)

    f32x4 hreg = {0.f, 0.f, 0.f, 0.f};
    float* op = out + ((size_t)b * T_N + m0) * U_N + u;
    __syncthreads();   // one-time full drain (staging + A_h zero visible)

    // --- prologue: x-part of step 0 into acc set P
    Acc P, Q;
    {
        f16x8 axf[4];
        #pragma unroll
        for (int kt = 0; kt < 4; ++kt)
            axf[kt] = *(const f16x8*)&A_x[bat][0][ln][kt * 32 + lg * 8];
        P.z  = {bz, bz, bz, bz};
        P.r  = {br, br, br, br};
        P.xh = {bxh, bxh, bxh, bxh};
        P.hh = {brh, brh, brh, brh};
        #pragma unroll
        for (int kt = 0; kt < 4; ++kt) {
            P.z  = __builtin_amdgcn_mfma_f32_16x16x32_f16(axf[kt], wzk[kt], P.z, 0, 0, 0);
            P.r  = __builtin_amdgcn_mfma_f32_16x16x32_f16(axf[kt], wrk[kt], P.r, 0, 0, 0);
            P.xh = __builtin_amdgcn_mfma_f32_16x16x32_f16(axf[kt], whk[kt], P.xh, 0, 0, 0);
        }
    }

    auto step = [&](int l, float4& xs, Acc& cur, Acc& nxt) {
        const int rbuf = l & 1, wbuf = (l + 1) & 1;
        // ---- critical path: A_h fragments -> 12 h-MFMAs into cur
        f16x8 ahf[4];
        #pragma unroll
        for (int kt = 0; kt < 4; ++kt)
            ahf[kt] = *(const f16x8*)&A_h[bat][rbuf][ln][kt * 32 + lg * 8];
        #pragma unroll
        for (int kt = 0; kt < 4; ++kt) {
            cur.z  = __builtin_amdgcn_mfma_f32_16x16x32_f16(ahf[kt], wzr[kt], cur.z, 0, 0, 0);
            cur.r  = __builtin_amdgcn_mfma_f32_16x16x32_f16(ahf[kt], wrr[kt], cur.r, 0, 0, 0);
            cur.hh = __builtin_amdgcn_mfma_f32_16x16x32_f16(ahf[kt], whr[kt], cur.hh, 0, 0, 0);
        }
        // ---- independent: x-part of step l+1 into nxt (fills idle slots)
        if (l + 1 < L_N) {
            f16x8 axf[4];
            #pragma unroll
            for (int kt = 0; kt < 4; ++kt)
                axf[kt] = *(const f16x8*)&A_x[bat][wbuf][ln][kt * 32 + lg * 8];
            nxt.z  = {bz, bz, bz, bz};
            nxt.r  = {br, br, br, br};
            nxt.xh = {bxh, bxh, bxh, bxh};
            nxt.hh = {brh, brh, brh, brh};
            #pragma unroll
            for (int kt = 0; kt < 4; ++kt) {
                nxt.z  = __builtin_amdgcn_mfma_f32_16x16x32_f16(axf[kt], wzk[kt], nxt.z, 0, 0, 0);
                nxt.r  = __builtin_amdgcn_mfma_f32_16x16x32_f16(axf[kt], wrk[kt], nxt.r, 0, 0, 0);
                nxt.xh = __builtin_amdgcn_mfma_f32_16x16x32_f16(axf[kt], whk[kt], nxt.xh, 0, 0, 0);
            }
        }
        // ---- gate fully in-register; h never leaves the lane
        #pragma unroll
        for (int e = 0; e < 4; ++e) {
            float z = sigmoid2_(cur.z[e]);
            float r = sigmoid2_(cur.r[e]);
            float c = fmaxf(0.f, fmaf(r, cur.hh[e], cur.xh[e]));
            float hn = fmaf(z, hreg[e] - c, c);
            hreg[e] = hn;
            A_h[bat][wbuf][m0 + e][hcol] = (_Float16)hn;  // transpose write (b16)
            op[(size_t)e * U_N] = hn;                      // global, fire-and-forget
        }
        op += P_N * U_N;
        // ---- stage x(l+2) into A_x[bat][rbuf]; prefetch x(l+4)
        if (l + 2 < L_N) {
            f16x4 v = {(_Float16)xs.x, (_Float16)xs.y, (_Float16)xs.z, (_Float16)xs.w};
            *(f16x4*)&A_x[bat][rbuf][sm][scp] = v;
            if (l + 4 < L_N)
                xs = *(const float4*)(xb + (size_t)((l + 4) * P_N + sm) * F_N + sc);
        }
        BAR();
    };

    for (int l = 0; l < L_N; l += 2) {
        step(l, xsB, P, Q);       // even l consumes xsB (holds x(l+2))
        step(l + 1, xsA, Q, P);   // odd  l consumes xsA
    }
}

extern "C" void kernel_launch(void* const* d_in, const int* in_sizes, int n_in,
                              void* d_out, int out_size, void* d_ws, size_t ws_size,
                              hipStream_t stream) {
    const float* inputs = (const float*)d_in[0];
    const float* kernel = (const float*)d_in[1];
    const float* rker   = (const float*)d_in[2];
    const float* bias   = (const float*)d_in[3];
    float* o = (float*)d_out;
    hipLaunchKernelGGL(skipgru_kernel, dim3(B_N / 2), dim3(NT), 0, stream,
                       inputs, kernel, rker, bias, o);
}

// Round 11
// 386.679 us; speedup vs baseline: 4.4740x; 4.4740x over previous
//
#include <hip/hip_runtime.h>
#include <hip/hip_bf16.h>

// SkipGRU: B=64, T=4096, F=128, U=128, P=16 -> 1024 chains of length 256.
// Dual-batch ILP monolith: 32 WGs x 8 waves (512 thr, 2 waves/SIMD).
// Each wave runs its 16-col u-slice for TWO batches (2*bid, 2*bid+1) as two
// interleaved independent dependency streams inside one instruction stream:
// the reads/MFMAs of stream B issue while stream A's chain executes, and the
// gates of A run in the shadow of B's MFMAs. Weights (96 VGPR) are SHARED
// between streams -- the register trick that 4-wave TLP (r6/r10) could not do.
// One lgkm-only barrier per interval; both batches advance one step/interval.

#define B_N 64
#define T_N 4096
#define F_N 128
#define U_N 128
#define P_N 16
#define L_N 256
#define NW 8
#define NT (NW * 64)   // 512 threads

#define LOG2E 1.4426950408889634f

typedef _Float16 f16x8 __attribute__((ext_vector_type(8)));
typedef _Float16 f16x4 __attribute__((ext_vector_type(4)));
typedef float f32x4 __attribute__((ext_vector_type(4)));

__device__ __forceinline__ float sigmoid2_(float y) {   // y pre-scaled by log2e
    return __builtin_amdgcn_rcpf(1.0f + __builtin_amdgcn_exp2f(-y));
}

// Position of logical k within a fragment-contiguous row:
// row[kt*32 + lg*8 + e] holds k = kt*32 + 16*(e>>2) + 4*lg + (e&3).
__device__ __forceinline__ int fpos(int k) {
    return ((k >> 5) << 5) + (((k >> 2) & 3) << 3) + (((k >> 4) & 1) << 2) + (k & 3);
}

// barrier with LDS-only drain; global loads/stores stay in flight
#define BAR() do { \
    asm volatile("s_waitcnt lgkmcnt(0)" ::: "memory"); \
    __builtin_amdgcn_s_barrier(); \
    __builtin_amdgcn_sched_barrier(0); \
} while (0)

__global__ __launch_bounds__(NT, 2) void skipgru_kernel(
    const float* __restrict__ xg, const float* __restrict__ Wk,
    const float* __restrict__ Wr, const float* __restrict__ bias,
    float* __restrict__ out)
{
    // Fragment-contiguous A operands per batch, padded rows (264 B) for banks.
    __shared__ __align__(16) _Float16 A_x[2][2][16][132];  // [bat][buf][m][k]
    __shared__ __align__(16) _Float16 A_h[2][2][16][132];

    const int tid  = threadIdx.x;
    const int lane = tid & 63;
    const int wave = tid >> 6;
    const int ln   = lane & 15;      // A-row / C-col index
    const int lg   = lane >> 4;      // k-group (A/B), row-group (C/D)
    const int u    = wave * 16 + ln; // this lane's output column
    const int m0   = lg * 4;         // this lane's C/D row base
    const int b0   = blockIdx.x * 2;
    const int hcol = fpos(u);        // A_h transpose-write column

    // --- per-lane bias scalars (z/r pre-summed and log2e-scaled) -- SHARED
    const float bz  = (bias[u]       + bias[384 + u])       * LOG2E;
    const float br  = (bias[128 + u] + bias[384 + 128 + u]) * LOG2E;
    const float bxh = bias[256 + u];
    const float brh = bias[384 + 256 + u];

    // --- weight fragments: 6 B-frag sets, z/r scaled by log2e -- SHARED
    f16x8 wzk[4], wzr[4], wrk[4], wrr[4], whk[4], whr[4];
    #pragma unroll
    for (int kt = 0; kt < 4; ++kt) {
        #pragma unroll
        for (int e = 0; e < 8; ++e) {
            int k = kt * 32 + ((e >> 2) << 4) + (lg << 2) + (e & 3);
            const float* wkp = Wk + (size_t)k * 384;
            const float* wrp = Wr + (size_t)k * 384;
            wzk[kt][e] = (_Float16)(wkp[u] * LOG2E);
            wzr[kt][e] = (_Float16)(wrp[u] * LOG2E);
            wrk[kt][e] = (_Float16)(wkp[128 + u] * LOG2E);
            wrr[kt][e] = (_Float16)(wrp[128 + u] * LOG2E);
            whk[kt][e] = (_Float16)wkp[256 + u];
            whr[kt][e] = (_Float16)wrp[256 + u];
        }
    }

    // --- zero A_h[*][0] (h(-P) = 0)
    for (int q = tid; q < 16 * 132; q += NT) {
        ((_Float16*)A_h[0][0])[q] = (_Float16)0;
        ((_Float16*)A_h[1][0])[q] = (_Float16)0;
    }

    // --- x staging map: thread -> (row sm, col-quad sc), frag position scp
    const int sm = tid & 15, sc = (tid >> 4) << 2;
    const int scp = fpos(sc);
    const float* xb0 = xg + (size_t)b0 * T_N * F_N;
    const float* xb1 = xb0 + (size_t)T_N * F_N;
    {
        float4 a0 = *(const float4*)(xb0 + (size_t)sm * F_N + sc);
        float4 a1 = *(const float4*)(xb0 + (size_t)(P_N + sm) * F_N + sc);
        float4 c0 = *(const float4*)(xb1 + (size_t)sm * F_N + sc);
        float4 c1 = *(const float4*)(xb1 + (size_t)(P_N + sm) * F_N + sc);
        f16x4 v;
        v = (f16x4){(_Float16)a0.x, (_Float16)a0.y, (_Float16)a0.z, (_Float16)a0.w};
        *(f16x4*)&A_x[0][0][sm][scp] = v;
        v = (f16x4){(_Float16)a1.x, (_Float16)a1.y, (_Float16)a1.z, (_Float16)a1.w};
        *(f16x4*)&A_x[0][1][sm][scp] = v;
        v = (f16x4){(_Float16)c0.x, (_Float16)c0.y, (_Float16)c0.z, (_Float16)c0.w};
        *(f16x4*)&A_x[1][0][sm][scp] = v;
        v = (f16x4){(_Float16)c1.x, (_Float16)c1.y, (_Float16)c1.z, (_Float16)c1.w};
        *(f16x4*)&A_x[1][1][sm][scp] = v;
    }
    float4 xs0B = *(const float4*)(xb0 + (size_t)(2 * P_N + sm) * F_N + sc);
    float4 xs0A = *(const float4*)(xb0 + (size_t)(3 * P_N + sm) * F_N + sc);
    float4 xs1B = *(const float4*)(xb1 + (size_t)(2 * P_N + sm) * F_N + sc);
    float4 xs1A = *(const float4*)(xb1 + (size_t)(3 * P_N + sm) * F_N + sc);

    f32x4 hr0 = {0.f, 0.f, 0.f, 0.f}, hr1 = {0.f, 0.f, 0.f, 0.f};
    float* op0 = out + ((size_t)b0 * T_N + m0) * U_N + u;
    float* op1 = op0 + (size_t)T_N * U_N;
    __syncthreads();   // one-time full drain

    // ---- per-batch helpers -------------------------------------------------
    auto mfma_batch = [&](int bat, int rbuf, f32x4& z, f32x4& r,
                          f32x4& xh, f32x4& hh) {
        f16x8 axf[4], ahf[4];
        #pragma unroll
        for (int kt = 0; kt < 4; ++kt) {
            axf[kt] = *(const f16x8*)&A_x[bat][rbuf][ln][kt * 32 + lg * 8];
            ahf[kt] = *(const f16x8*)&A_h[bat][rbuf][ln][kt * 32 + lg * 8];
        }
        z  = (f32x4){bz, bz, bz, bz};
        r  = (f32x4){br, br, br, br};
        xh = (f32x4){bxh, bxh, bxh, bxh};
        hh = (f32x4){brh, brh, brh, brh};
        #pragma unroll
        for (int kt = 0; kt < 4; ++kt) {
            z  = __builtin_amdgcn_mfma_f32_16x16x32_f16(axf[kt], wzk[kt], z, 0, 0, 0);
            r  = __builtin_amdgcn_mfma_f32_16x16x32_f16(axf[kt], wrk[kt], r, 0, 0, 0);
            xh = __builtin_amdgcn_mfma_f32_16x16x32_f16(axf[kt], whk[kt], xh, 0, 0, 0);
        }
        #pragma unroll
        for (int kt = 0; kt < 4; ++kt) {
            z  = __builtin_amdgcn_mfma_f32_16x16x32_f16(ahf[kt], wzr[kt], z, 0, 0, 0);
            r  = __builtin_amdgcn_mfma_f32_16x16x32_f16(ahf[kt], wrr[kt], r, 0, 0, 0);
            hh = __builtin_amdgcn_mfma_f32_16x16x32_f16(ahf[kt], whr[kt], hh, 0, 0, 0);
        }
    };
    auto gate_batch = [&](int bat, int wbuf, f32x4& z, f32x4& r,
                          f32x4& xh, f32x4& hh, f32x4& hreg, float* op) {
        #pragma unroll
        for (int e = 0; e < 4; ++e) {
            float zg = sigmoid2_(z[e]);
            float rg = sigmoid2_(r[e]);
            float c  = fmaxf(0.f, fmaf(rg, hh[e], xh[e]));
            float hn = fmaf(zg, hreg[e] - c, c);
            hreg[e] = hn;
            A_h[bat][wbuf][m0 + e][hcol] = (_Float16)hn;  // transpose write
            op[(size_t)e * U_N] = hn;                      // fire-and-forget
        }
    };
    auto stage_batch = [&](int bat, int rbuf, int l, const float* xb, float4& xs) {
        if (l + 2 < L_N) {
            f16x4 v = {(_Float16)xs.x, (_Float16)xs.y, (_Float16)xs.z, (_Float16)xs.w};
            *(f16x4*)&A_x[bat][rbuf][sm][scp] = v;
            if (l + 4 < L_N)
                xs = *(const float4*)(xb + (size_t)((l + 4) * P_N + sm) * F_N + sc);
        }
    };

    auto interval = [&](int l, float4& xs0, float4& xs1) {
        const int rbuf = l & 1, wbuf = (l + 1) & 1;
        f32x4 z0, r0, xh0, hh0, z1, r1, xh1, hh1;
        mfma_batch(0, rbuf, z0, r0, xh0, hh0);   // stream A: reads + 24 MFMA
        mfma_batch(1, rbuf, z1, r1, xh1, hh1);   // stream B issues in A's shadow
        gate_batch(0, wbuf, z0, r0, xh0, hh0, hr0, op0);  // runs under B's MFMAs
        stage_batch(0, rbuf, l, xb0, xs0);
        gate_batch(1, wbuf, z1, r1, xh1, hh1, hr1, op1);
        stage_batch(1, rbuf, l, xb1, xs1);
        op0 += P_N * U_N; op1 += P_N * U_N;
        BAR();
    };

    for (int l = 0; l < L_N; l += 2) {
        interval(l, xs0B, xs1B);       // even l consumes xs*B (holds x(l+2))
        interval(l + 1, xs0A, xs1A);   // odd  l consumes xs*A
    }
}

extern "C" void kernel_launch(void* const* d_in, const int* in_sizes, int n_in,
                              void* d_out, int out_size, void* d_ws, size_t ws_size,
                              hipStream_t stream) {
    const float* inputs = (const float*)d_in[0];
    const float* kernel = (const float*)d_in[1];
    const float* rker   = (const float*)d_in[2];
    const float* bias   = (const float*)d_in[3];
    float* o = (float*)d_out;
    hipLaunchKernelGGL(skipgru_kernel, dim3(B_N / 2), dim3(NT), 0, stream,
                       inputs, kernel, rker, bias, o);
}

// Round 12
// 346.291 us; speedup vs baseline: 4.9958x; 1.1166x over previous
//
#include <hip/hip_runtime.h>
#include <hip/hip_bf16.h>

// SkipGRU: B=64, T=4096, F=128, U=128, P=16 -> 1024 chains of length 256.
// Dual-batch ILP monolith, take 2: 32 WGs x 8 waves (512 thr, 2 waves/SIMD).
// Each wave runs its 16-col u-slice for TWO batches as two independent
// dependency streams in one instruction stream. Weights (96 VGPR) + biases
// are SHARED and PINNED via asm "+v" so the register allocator cannot
// rematerialize their global loads inside the loop (r11's failure: VGPR=104
// proved weights were reloaded every step -> streams serialized at 2x).

#define B_N 64
#define T_N 4096
#define F_N 128
#define U_N 128
#define P_N 16
#define L_N 256
#define NW 8
#define NT (NW * 64)   // 512 threads

#define LOG2E 1.4426950408889634f

typedef _Float16 f16x8 __attribute__((ext_vector_type(8)));
typedef _Float16 f16x4 __attribute__((ext_vector_type(4)));
typedef float f32x4 __attribute__((ext_vector_type(4)));

__device__ __forceinline__ float sigmoid2_(float y) {   // y pre-scaled by log2e
    return __builtin_amdgcn_rcpf(1.0f + __builtin_amdgcn_exp2f(-y));
}

// Position of logical k within a fragment-contiguous row:
// row[kt*32 + lg*8 + e] holds k = kt*32 + 16*(e>>2) + 4*lg + (e&3).
__device__ __forceinline__ int fpos(int k) {
    return ((k >> 5) << 5) + (((k >> 2) & 3) << 3) + (((k >> 4) & 1) << 2) + (k & 3);
}

// barrier with LDS-only drain; global loads/stores stay in flight
#define BAR() do { \
    asm volatile("s_waitcnt lgkmcnt(0)" ::: "memory"); \
    __builtin_amdgcn_s_barrier(); \
    __builtin_amdgcn_sched_barrier(0); \
} while (0)

#define MFMA __builtin_amdgcn_mfma_f32_16x16x32_f16
#define PIN4(a,b,c,d) asm volatile("" : "+v"(a), "+v"(b), "+v"(c), "+v"(d))

__global__ __launch_bounds__(NT, 2) void skipgru_kernel(
    const float* __restrict__ xg, const float* __restrict__ Wk,
    const float* __restrict__ Wr, const float* __restrict__ bias,
    float* __restrict__ out)
{
    // Fragment-contiguous A operands per batch, padded rows (264 B) for banks.
    __shared__ __align__(16) _Float16 A_x[2][2][16][132];  // [bat][buf][m][k]
    __shared__ __align__(16) _Float16 A_h[2][2][16][132];

    const int tid  = threadIdx.x;
    const int lane = tid & 63;
    const int wave = tid >> 6;
    const int ln   = lane & 15;      // A-row / C-col index
    const int lg   = lane >> 4;      // k-group (A/B), row-group (C/D)
    const int u    = wave * 16 + ln; // this lane's output column
    const int m0   = lg * 4;         // this lane's C/D row base
    const int b0   = blockIdx.x * 2;
    const int hcol = fpos(u);        // A_h transpose-write column

    // --- per-lane bias scalars (z/r pre-summed and log2e-scaled) -- SHARED
    float bz  = (bias[u]       + bias[384 + u])       * LOG2E;
    float br  = (bias[128 + u] + bias[384 + 128 + u]) * LOG2E;
    float bxh = bias[256 + u];
    float brh = bias[384 + 256 + u];

    // --- weight fragments: 6 B-frag sets, z/r scaled by log2e -- SHARED
    f16x8 wzk[4], wzr[4], wrk[4], wrr[4], whk[4], whr[4];
    #pragma unroll
    for (int kt = 0; kt < 4; ++kt) {
        #pragma unroll
        for (int e = 0; e < 8; ++e) {
            int k = kt * 32 + ((e >> 2) << 4) + (lg << 2) + (e & 3);
            const float* wkp = Wk + (size_t)k * 384;
            const float* wrp = Wr + (size_t)k * 384;
            wzk[kt][e] = (_Float16)(wkp[u] * LOG2E);
            wzr[kt][e] = (_Float16)(wrp[u] * LOG2E);
            wrk[kt][e] = (_Float16)(wkp[128 + u] * LOG2E);
            wrr[kt][e] = (_Float16)(wrp[128 + u] * LOG2E);
            whk[kt][e] = (_Float16)wkp[256 + u];
            whr[kt][e] = (_Float16)wrp[256 + u];
        }
    }
    // PIN: make weight/bias values asm-defined -> allocator cannot remat the
    // global loads inside the loop (this is what killed r11: VGPR=104).
    PIN4(wzk[0], wzk[1], wzk[2], wzk[3]);
    PIN4(wzr[0], wzr[1], wzr[2], wzr[3]);
    PIN4(wrk[0], wrk[1], wrk[2], wrk[3]);
    PIN4(wrr[0], wrr[1], wrr[2], wrr[3]);
    PIN4(whk[0], whk[1], whk[2], whk[3]);
    PIN4(whr[0], whr[1], whr[2], whr[3]);
    PIN4(bz, br, bxh, brh);

    // --- zero A_h[*][0] (h(-P) = 0)
    for (int q = tid; q < 16 * 132; q += NT) {
        ((_Float16*)A_h[0][0])[q] = (_Float16)0;
        ((_Float16*)A_h[1][0])[q] = (_Float16)0;
    }

    // --- x staging map: thread -> (row sm, col-quad sc), frag position scp
    const int sm = tid & 15, sc = (tid >> 4) << 2;
    const int scp = fpos(sc);
    const float* xb0 = xg + (size_t)b0 * T_N * F_N;
    const float* xb1 = xb0 + (size_t)T_N * F_N;
    {
        float4 a0 = *(const float4*)(xb0 + (size_t)sm * F_N + sc);
        float4 a1 = *(const float4*)(xb0 + (size_t)(P_N + sm) * F_N + sc);
        float4 c0 = *(const float4*)(xb1 + (size_t)sm * F_N + sc);
        float4 c1 = *(const float4*)(xb1 + (size_t)(P_N + sm) * F_N + sc);
        f16x4 v;
        v = (f16x4){(_Float16)a0.x, (_Float16)a0.y, (_Float16)a0.z, (_Float16)a0.w};
        *(f16x4*)&A_x[0][0][sm][scp] = v;
        v = (f16x4){(_Float16)a1.x, (_Float16)a1.y, (_Float16)a1.z, (_Float16)a1.w};
        *(f16x4*)&A_x[0][1][sm][scp] = v;
        v = (f16x4){(_Float16)c0.x, (_Float16)c0.y, (_Float16)c0.z, (_Float16)c0.w};
        *(f16x4*)&A_x[1][0][sm][scp] = v;
        v = (f16x4){(_Float16)c1.x, (_Float16)c1.y, (_Float16)c1.z, (_Float16)c1.w};
        *(f16x4*)&A_x[1][1][sm][scp] = v;
    }
    float4 xs0B = *(const float4*)(xb0 + (size_t)(2 * P_N + sm) * F_N + sc);
    float4 xs0A = *(const float4*)(xb0 + (size_t)(3 * P_N + sm) * F_N + sc);
    float4 xs1B = *(const float4*)(xb1 + (size_t)(2 * P_N + sm) * F_N + sc);
    float4 xs1A = *(const float4*)(xb1 + (size_t)(3 * P_N + sm) * F_N + sc);

    f32x4 hr0 = {0.f, 0.f, 0.f, 0.f}, hr1 = {0.f, 0.f, 0.f, 0.f};
    float* op0 = out + ((size_t)b0 * T_N + m0) * U_N + u;
    float* op1 = op0 + (size_t)T_N * U_N;
    __syncthreads();   // one-time full drain

    // ---- one barrier interval: both batches advance one step ---------------
    auto interval = [&](int l, float4& xs0, float4& xs1) {
        const int rbuf = l & 1, wbuf = (l + 1) & 1;
        // all 16 ds_read_b128 issued up front
        f16x8 ax0[4], ah0[4], ax1[4], ah1[4];
        #pragma unroll
        for (int kt = 0; kt < 4; ++kt) {
            ax0[kt] = *(const f16x8*)&A_x[0][rbuf][ln][kt * 32 + lg * 8];
            ah0[kt] = *(const f16x8*)&A_h[0][rbuf][ln][kt * 32 + lg * 8];
            ax1[kt] = *(const f16x8*)&A_x[1][rbuf][ln][kt * 32 + lg * 8];
            ah1[kt] = *(const f16x8*)&A_h[1][rbuf][ln][kt * 32 + lg * 8];
        }
        // stream 0: 24 MFMAs (x-part then h-part), bias C-init
        f32x4 z0  = {bz, bz, bz, bz},     r0  = {br, br, br, br};
        f32x4 xh0 = {bxh, bxh, bxh, bxh}, hh0 = {brh, brh, brh, brh};
        #pragma unroll
        for (int kt = 0; kt < 4; ++kt) {
            z0  = MFMA(ax0[kt], wzk[kt], z0, 0, 0, 0);
            r0  = MFMA(ax0[kt], wrk[kt], r0, 0, 0, 0);
            xh0 = MFMA(ax0[kt], whk[kt], xh0, 0, 0, 0);
        }
        #pragma unroll
        for (int kt = 0; kt < 4; ++kt) {
            z0  = MFMA(ah0[kt], wzr[kt], z0, 0, 0, 0);
            r0  = MFMA(ah0[kt], wrr[kt], r0, 0, 0, 0);
            hh0 = MFMA(ah0[kt], whr[kt], hh0, 0, 0, 0);
        }
        // stream 1: fully independent 24 MFMAs
        f32x4 z1  = {bz, bz, bz, bz},     r1  = {br, br, br, br};
        f32x4 xh1 = {bxh, bxh, bxh, bxh}, hh1 = {brh, brh, brh, brh};
        #pragma unroll
        for (int kt = 0; kt < 4; ++kt) {
            z1  = MFMA(ax1[kt], wzk[kt], z1, 0, 0, 0);
            r1  = MFMA(ax1[kt], wrk[kt], r1, 0, 0, 0);
            xh1 = MFMA(ax1[kt], whk[kt], xh1, 0, 0, 0);
        }
        #pragma unroll
        for (int kt = 0; kt < 4; ++kt) {
            z1  = MFMA(ah1[kt], wzr[kt], z1, 0, 0, 0);
            r1  = MFMA(ah1[kt], wrr[kt], r1, 0, 0, 0);
            hh1 = MFMA(ah1[kt], whr[kt], hh1, 0, 0, 0);
        }
        // gates fully in-register; h never leaves the lane
        #pragma unroll
        for (int e = 0; e < 4; ++e) {
            float zg = sigmoid2_(z0[e]);
            float rg = sigmoid2_(r0[e]);
            float c  = fmaxf(0.f, fmaf(rg, hh0[e], xh0[e]));
            float hn = fmaf(zg, hr0[e] - c, c);
            hr0[e] = hn;
            A_h[0][wbuf][m0 + e][hcol] = (_Float16)hn;
            op0[(size_t)e * U_N] = hn;
        }
        #pragma unroll
        for (int e = 0; e < 4; ++e) {
            float zg = sigmoid2_(z1[e]);
            float rg = sigmoid2_(r1[e]);
            float c  = fmaxf(0.f, fmaf(rg, hh1[e], xh1[e]));
            float hn = fmaf(zg, hr1[e] - c, c);
            hr1[e] = hn;
            A_h[1][wbuf][m0 + e][hcol] = (_Float16)hn;
            op1[(size_t)e * U_N] = hn;
        }
        // stage x(l+2) into A_x[*][rbuf]; prefetch x(l+4)
        if (l + 2 < L_N) {
            f16x4 v0 = {(_Float16)xs0.x, (_Float16)xs0.y, (_Float16)xs0.z, (_Float16)xs0.w};
            f16x4 v1 = {(_Float16)xs1.x, (_Float16)xs1.y, (_Float16)xs1.z, (_Float16)xs1.w};
            *(f16x4*)&A_x[0][rbuf][sm][scp] = v0;
            *(f16x4*)&A_x[1][rbuf][sm][scp] = v1;
            if (l + 4 < L_N) {
                xs0 = *(const float4*)(xb0 + (size_t)((l + 4) * P_N + sm) * F_N + sc);
                xs1 = *(const float4*)(xb1 + (size_t)((l + 4) * P_N + sm) * F_N + sc);
            }
        }
        op0 += P_N * U_N; op1 += P_N * U_N;
        BAR();
    };

    for (int l = 0; l < L_N; l += 2) {
        interval(l, xs0B, xs1B);       // even l consumes xs*B (holds x(l+2))
        interval(l + 1, xs0A, xs1A);   // odd  l consumes xs*A
    }
}

extern "C" void kernel_launch(void* const* d_in, const int* in_sizes, int n_in,
                              void* d_out, int out_size, void* d_ws, size_t ws_size,
                              hipStream_t stream) {
    const float* inputs = (const float*)d_in[0];
    const float* kernel = (const float*)d_in[1];
    const float* rker   = (const float*)d_in[2];
    const float* bias   = (const float*)d_in[3];
    float* o = (float*)d_out;
    hipLaunchKernelGGL(skipgru_kernel, dim3(B_N / 2), dim3(NT), 0, stream,
                       inputs, kernel, rker, bias, o);
}